// Round 4
// baseline (750.484 us; speedup 1.0000x reference)
//
#include <hip/hip_runtime.h>
#include <hip/hip_bf16.h>

// Problem dims
#define B_    4
#define T_    512
#define H_    768
#define N_    256
#define S_    16
#define NERD  32
#define D_    800      // H + NER_DIM
#define L_    2
#define R_    15
#define NE_   64
#define MM_   8
#define P_    1024
#define E_    4096
#define OUT_  97
#define NW    12800        // GNN GEMM width: R*D + D  ([W_rel | W_self])
#define EE2   1600         // 2*D
#define KF    (4 * EE2)    // 6400
#define NH    (2 * EE2)    // 3200
#define NPAD  3328         // 13*256  (N-padded W1cdT rows for 256-tile GEMM)
#define KS    800          // mlp2 K-split slice
#define NZ    4            // mlp2 K-split count

typedef unsigned short u16;
typedef unsigned int   u32;
typedef __attribute__((ext_vector_type(8))) short  short8;
typedef __attribute__((ext_vector_type(4))) float  f32x4;

#define AS1 __attribute__((address_space(1)))
#define AS3 __attribute__((address_space(3)))

static __device__ __forceinline__ u16 f2bf(float f) {
  union { float f; u32 u; } v; v.f = f;
  u32 u = v.u;
  u32 r = (u + 0x7FFFu + ((u >> 16) & 1u)) >> 16;  // round-nearest-even
  return (u16)r;
}
static __device__ __forceinline__ float bf2f(u16 h) {
  union { u32 u; float f; } v; v.u = ((u32)h) << 16;
  return v.f;
}

// ---------------------------------------------------------------- doc_proj
__global__ __launch_bounds__(256) void k_doc_proj(
    const float* __restrict__ doc_cls, const float* __restrict__ doc_W,
    const float* __restrict__ doc_b, float* __restrict__ doc_proj) {
  int i = blockIdx.x * 256 + threadIdx.x;
  if (i >= B_ * D_) return;
  int b = i / D_, d = i % D_;
  float acc = doc_b[d];
  const float* dc = doc_cls + b * H_;
#pragma unroll 4
  for (int k = 0; k < H_; k++) acc += dc[k] * doc_W[k * D_ + d];
  doc_proj[i] = fmaxf(acc, 0.f);
}

// ---------------------------------------------------------------- node build -> xB (bf16)
__global__ __launch_bounds__(256) void k_build_node(
    const float* __restrict__ tokf, const float* __restrict__ doc_cls,
    const int* __restrict__ span_pos, const float* __restrict__ span_mask,
    const int* __restrict__ node_ner, const float* __restrict__ node_mask,
    const int* __restrict__ ment_num, const float* __restrict__ nerEmb,
    const float* __restrict__ doc_proj, u16* __restrict__ xB) {
  int n = blockIdx.x, b = blockIdx.y;
  __shared__ int pos_s[S_];
  __shared__ float msk_s[S_];
  int tid = threadIdx.x;
  if (tid < S_) {
    pos_s[tid] = span_pos[((size_t)b * N_ + n) * S_ + tid];
    msk_s[tid] = span_mask[((size_t)b * N_ + n) * S_ + tid];
  }
  __syncthreads();
  float msum = 0.f;
#pragma unroll
  for (int s = 0; s < S_; s++) msum += msk_s[s];
  float rinv = 1.f / (msum + 0.1f);
  int m = ment_num[b];
  float nm = node_mask[b * N_ + n];
  int ner = node_ner[b * N_ + n];
  for (int d = tid; d < D_; d += 256) {
    float v;
    if (d < H_) {
      float ssum = 0.f;
#pragma unroll
      for (int s = 0; s < S_; s++)
        ssum += tokf[((size_t)b * T_ + pos_s[s]) * H_ + d] * msk_s[s];
      v = ssum * rinv + doc_cls[b * H_ + d];
    } else {
      v = nerEmb[ner * NERD + (d - H_)];
    }
    v *= nm;
    if (n == m) v = doc_proj[b * D_ + d];
    xB[((size_t)b * N_ + n) * D_ + d] = f2bf(v);
  }
}

// ---------------------------------------------------------------- GNN weight transpose
__global__ __launch_bounds__(256) void k_wt(const float* __restrict__ W_rel,
                                            const float* __restrict__ W_self,
                                            u16* __restrict__ WT) {
  __shared__ float tile[32][33];
  int l = blockIdx.z >> 4, i = blockIdx.z & 15;
  const float* src = (i < 15) ? (W_rel + ((size_t)l * R_ + i) * D_ * D_)
                              : (W_self + (size_t)l * D_ * D_);
  u16* dst = WT + (size_t)l * NW * D_ + (size_t)i * D_ * D_;
  int d0 = blockIdx.x * 32, e0 = blockIdx.y * 32;
  int tx = threadIdx.x & 31, ty = threadIdx.x >> 5;
  for (int j = ty; j < 32; j += 8)
    tile[j][tx] = src[(size_t)(d0 + j) * D_ + e0 + tx];
  __syncthreads();
  for (int j = ty; j < 32; j += 8)
    dst[(size_t)(e0 + j) * D_ + d0 + tx] = f2bf(tile[tx][j]);
}

// ---------------------------------------------------------------- W1 transpose:
// W1 (KF x NH fp32) ->  W1abT (6400 x 1600 bf16)  rows: n for a-part, 3200+n for b-part
//                       W1cdT (NPAD x 3200 bf16)  rows: n, k = kcol-3200 (rows >=NH zero-padded)
__global__ __launch_bounds__(256) void k_w1t(const float* __restrict__ W1,
                                             u16* __restrict__ W1abT,
                                             u16* __restrict__ W1cdT) {
  __shared__ float tile[32][33];
  int k0 = blockIdx.x * 32, n0 = blockIdx.y * 32;
  int tx = threadIdx.x & 31, ty = threadIdx.x >> 5;
  for (int i = ty; i < 32; i += 8)
    tile[i][tx] = W1[(size_t)(k0 + i) * NH + n0 + tx];
  __syncthreads();
  for (int i = ty; i < 32; i += 8) {
    int kk = k0 + tx, n = n0 + i;
    u16 v = f2bf(tile[tx][i]);
    if (kk < EE2)            W1abT[(size_t)n * EE2 + kk] = v;
    else if (kk < 2 * EE2)   W1abT[(size_t)(NH + n) * EE2 + (kk - EE2)] = v;
    else                     W1cdT[(size_t)n * NH + (kk - 2 * EE2)] = v;
  }
}

// zero the N-pad rows of W1cdT (rows NH..NPAD-1), 128*3200 u16 = 204800 u32
__global__ __launch_bounds__(256) void k_w1cd_pad(u16* __restrict__ W1cdT) {
  size_t i = (size_t)blockIdx.x * 256 + threadIdx.x;   // 0..204799
  ((u32*)(W1cdT + (size_t)NH * NH))[i] = 0u;
}

// ---------------------------------------------------------------- W2 transpose: W2 (NH x 97 fp32) -> W2T (128 x NH bf16), pad rows zero
__global__ __launch_bounds__(256) void k_w2t(const float* __restrict__ W2,
                                             u16* __restrict__ W2T) {
  __shared__ float tile[32][33];
  int k0 = blockIdx.x * 32, n0 = blockIdx.y * 32;
  int tx = threadIdx.x & 31, ty = threadIdx.x >> 5;
  for (int i = ty; i < 32; i += 8)
    tile[i][tx] = (n0 + tx < OUT_) ? W2[(size_t)(k0 + i) * OUT_ + n0 + tx] : 0.f;
  __syncthreads();
  for (int i = ty; i < 32; i += 8)
    W2T[(size_t)(n0 + i) * NH + k0 + tx] = f2bf(tile[tx][i]);
}

// ---------------------------------------------------------------- CSR build
__global__ __launch_bounds__(256) void k_csr_zero(int* __restrict__ cnt) {
  cnt[blockIdx.x * 256 + threadIdx.x] = 0;
}
__global__ __launch_bounds__(256) void k_csr_count(const int* __restrict__ edst,
                                                   int* __restrict__ cnt) {
  int e = blockIdx.x * 256 + threadIdx.x, b = blockIdx.y;
  atomicAdd(&cnt[b * N_ + edst[(size_t)b * E_ + e]], 1);
}
__global__ __launch_bounds__(256) void k_csr_scan(const int* __restrict__ cnt,
                                                  int* __restrict__ rowptr,
                                                  int* __restrict__ cursor) {
  int b = blockIdx.x, t = threadIdx.x;
  __shared__ int s[N_];
  int own = cnt[b * N_ + t];
  s[t] = own;
  __syncthreads();
  for (int off = 1; off < N_; off <<= 1) {
    int v = (t >= off) ? s[t - off] : 0;
    __syncthreads();
    s[t] += v;
    __syncthreads();
  }
  int excl = s[t] - own;
  rowptr[b * (N_ + 1) + t] = excl;
  cursor[b * N_ + t] = excl;
  if (t == 0) rowptr[b * (N_ + 1) + N_] = E_;
}
__global__ __launch_bounds__(256) void k_csr_fill(
    const int* __restrict__ esrc, const int* __restrict__ edst,
    const int* __restrict__ erel, int* __restrict__ cursor,
    int* __restrict__ elist) {
  int e = blockIdx.x * 256 + threadIdx.x, b = blockIdx.y;
  size_t ei = (size_t)b * E_ + e;
  int pos = atomicAdd(&cursor[b * N_ + edst[ei]], 1);
  elist[b * E_ + pos] = esrc[ei] | (erel[ei] << 9);
}

// ---------------------------------------------------------------- generic bf16 MFMA GEMM (m97-style)
// C = A[M x K](lda) @ B[N x K](ldb)^T ; 128x128 tile, BK=32, group-M swizzle.
// EPI: 0 = bf16 plain, 1 = f32 plain, 4 = f32 acc + (col<NH ? bias[col] : 0)
template <int KD, int EPI>
__global__ __launch_bounds__(256) void k_gemm_bt(
    const u16* __restrict__ A, int lda, const u16* __restrict__ Bm, int ldb,
    const float* __restrict__ bias, const float* __restrict__ preA,
    const float* __restrict__ preB, const int* __restrict__ pairs,
    void* __restrict__ Cv, int ldc, int ldpre, long long zA, long long zC) {
  __shared__ u16 As[128 * 32];
  __shared__ u16 Bs[128 * 32];
  int tid = threadIdx.x;
  int w = tid >> 6, lane = tid & 63;
  int wr = w >> 1, wc = w & 1;
  int lane16 = lane & 15, quad = lane >> 4;

  // group-M swizzle for L2 locality
  int nbn = gridDim.x, nbm = gridDim.y;
  int pid = blockIdx.y * nbn + blockIdx.x;
  const int GROUP = 8;
  int npg = GROUP * nbn;
  int gidg = pid / npg;
  int first = gidg * GROUP;
  int szm = min(nbm - first, GROUP);
  int pid_m = first + (pid % npg) % szm;
  int pid_n = (pid % npg) / szm;
  int n0 = pid_n * 128;
  int m0 = pid_m * 128;

  int lrow = lane >> 2;              // 0..15
  int lcol = (lane & 3) * 8;         // ushort offset within 32-col row

  f32x4 acc[4][4] = {};

  const u16* gA = A + (size_t)blockIdx.z * zA + (size_t)m0 * lda;
  const u16* gB = Bm + (size_t)blockIdx.z * zA + (size_t)n0 * ldb;

  for (int kt = 0; kt < KD; kt += 32) {
    __syncthreads();
#pragma unroll
    for (int j = 0; j < 2; j++) {
      int chunk = j * 4 + w;
      int row = chunk * 16 + lrow;
      __builtin_amdgcn_global_load_lds(
          (const AS1 void*)(gA + (size_t)row * lda + kt + lcol),
          (AS3 void*)(As + chunk * 512 + lane * 8), 16, 0, 0);
      __builtin_amdgcn_global_load_lds(
          (const AS1 void*)(gB + (size_t)row * ldb + kt + lcol),
          (AS3 void*)(Bs + chunk * 512 + lane * 8), 16, 0, 0);
    }
    __syncthreads();

    short8 af[4], bf[4];
#pragma unroll
    for (int mi = 0; mi < 4; mi++) {
      int ml = wr * 64 + mi * 16 + lane16;
      af[mi] = *(const short8*)(As + ml * 32 + quad * 8);
    }
#pragma unroll
    for (int ni = 0; ni < 4; ni++) {
      int nl = wc * 64 + ni * 16 + lane16;
      bf[ni] = *(const short8*)(Bs + nl * 32 + quad * 8);
    }
#pragma unroll
    for (int mi = 0; mi < 4; mi++)
#pragma unroll
      for (int ni = 0; ni < 4; ni++)
        acc[mi][ni] = __builtin_amdgcn_mfma_f32_16x16x32_bf16(
            af[mi], bf[ni], acc[mi][ni], 0, 0, 0);
  }

  // epilogue: D layout col=lane&15, row=quad*4+reg
  int cols[4];
  float bv[4];
#pragma unroll
  for (int ni = 0; ni < 4; ni++) {
    cols[ni] = n0 + wc * 64 + ni * 16 + lane16;
    if (EPI == 4) bv[ni] = (cols[ni] < NH) ? bias[cols[ni]] : 0.f;
  }
  float* Cf = (float*)Cv + (size_t)blockIdx.z * zC;
#pragma unroll
  for (int mi = 0; mi < 4; mi++) {
#pragma unroll
    for (int r = 0; r < 4; r++) {
      int row = m0 + wr * 64 + mi * 16 + quad * 4 + r;
#pragma unroll
      for (int ni = 0; ni < 4; ni++) {
        float v = acc[mi][ni][r];
        int col = cols[ni];
        if (EPI == 0) {
          ((u16*)Cv)[(size_t)row * ldc + col] = f2bf(v);
        } else if (EPI == 1) {
          Cf[(size_t)row * ldc + col] = v;
        } else if (EPI == 4) {
          Cf[(size_t)row * ldc + col] = v + bv[ni];
        }
      }
    }
  }
}

// ---------------------------------------------------------------- 256x256 8-phase GEMM (T2+T3+T4+T5)
// hidden = relu(featC @ W1cdT^T + preAB[hp][col] + preAB[tp][NH+col]), bf16 out.
// A = featC (4096 x 3200), B = W1cdT (NPAD x 3200), grid (13, 16), 512 thr (8 waves 2Mx4N).
// r3 quadrant phasing (reads 12/4/8/0, MFMA = one C-quadrant x K=64 per phase) but
// with PLAIN C++ ds_reads (m201-style): the compiler emits fine-grained counted
// lgkmcnt per consuming MFMA, interleaving read-completion with MFMA issue —
// the read||MFMA overlap the bulk asm lgkmcnt(0) of r3 destroyed.
// Raw s_barrier (no vmcnt fence); counted vmcnt(6) once per K-tile via asm.
__global__ __launch_bounds__(512, 2) void k_gemm8p(
    const u16* __restrict__ A, const u16* __restrict__ Bm,
    const float* __restrict__ preAB_, const int* __restrict__ pairs,
    u16* __restrict__ C) {
  __shared__ u16 lds[2][2][2][128 * 64];   // 131072 B; strides: buf 65536, A/B 32768, half 16384

  int tid = threadIdx.x;
  int w = tid >> 6, lane = tid & 63;
  int wr = w >> 2, wc = w & 3;             // 2 x 4 wave grid
  int lane16 = lane & 15, quad = lane >> 4;

  // XCD-aware swizzle: nwg = 208 = 8*26 (divisible -> simple bijective form)
  int pid = blockIdx.y * 13 + blockIdx.x;
  pid = (pid & 7) * 26 + (pid >> 3);
  int pid_m = pid / 13, pid_n = pid % 13;
  int m0 = pid_m * 256, n0 = pid_n * 256;

  // staging per-thread constants: row-in-quarter + pre-swizzled source granule
  int srow = (w << 3) + (lane >> 3);                 // 0..63
  int g8 = ((lane & 7) ^ (lane >> 3)) << 3;          // source col elems (granule*8)
  const u16* gAt = A + (size_t)(m0 + srow) * NH + g8;
  const u16* gBt = Bm + (size_t)(n0 + srow) * NH + g8;
  int ldsSlot = ((w << 6) + lane) << 3;              // u16 elems within half

  // one STAGE = one 128x64 half-tile = 2 x global_load_lds(16B) per thread
#define STAGE(buf, ab, h, kt)                                                  \
  do {                                                                         \
    const u16* gsrc_ = (ab) ? gBt : gAt;                                       \
    __builtin_amdgcn_global_load_lds(                                          \
        (const AS1 void*)(gsrc_ + (size_t)((h)*128) * NH + (kt)),              \
        (AS3 void*)(&lds[buf][ab][h][0] + ldsSlot), 16, 0, 0);                 \
    __builtin_amdgcn_global_load_lds(                                          \
        (const AS1 void*)(gsrc_ + (size_t)((h)*128 + 64) * NH + (kt)),         \
        (AS3 void*)(&lds[buf][ab][h][0] + 4096 + ldsSlot), 16, 0, 0);          \
  } while (0)

  // plain-C++ swizzled fragment reads (compiler tracks deps -> counted lgkm)
  auto rdA = [&](int buf, int mi, int ks) -> short8 {
    int rh = mi * 16 + lane16;
    int p = ((ks << 2) + quad) ^ (lane16 & 7);
    return *(const short8*)(&lds[buf][0][wr][(rh << 6) + (p << 3)]);
  };
  auto rdB = [&](int buf, int ni, int ks) -> short8 {
    int rh = ((wc & 1) << 6) + ni * 16 + lane16;
    int p = ((ks << 2) + quad) ^ (lane16 & 7);
    return *(const short8*)(&lds[buf][1][wc >> 1][(rh << 6) + (p << 3)]);
  };

  f32x4 acc[8][4] = {};
  short8 a_[4][2];     // current A quarter (lo in P1-P2, hi in P3-P4)
  short8 bL[2][2];     // ni{0,1} x ks, held P1 -> P4
  short8 bH[2][2];     // ni{2,3} x ks, held P2 -> P3

  // one C-quadrant x K=64: 8 acc tiles, each a K-chained MFMA pair
#define MMQ(MI0, NI0, BB)                                                      \
  { _Pragma("unroll") for (int mi_ = 0; mi_ < 4; ++mi_) {                      \
      _Pragma("unroll") for (int ni_ = 0; ni_ < 2; ++ni_) {                    \
        f32x4 t_ = __builtin_amdgcn_mfma_f32_16x16x32_bf16(                    \
            a_[mi_][0], BB[ni_][0], acc[(MI0) + mi_][(NI0) + ni_], 0, 0, 0);   \
        acc[(MI0) + mi_][(NI0) + ni_] =                                        \
            __builtin_amdgcn_mfma_f32_16x16x32_bf16(a_[mi_][1], BB[ni_][1],    \
                                                    t_, 0, 0, 0);              \
      } } }

  // one K-tile (K=64) in buf HB; OB = other buf. 4 quadrant phases.
#define K_TILE(HB, OB, ktB1, kt2)                                              \
  /* P1: read A-lo(8) + B-lo(4); stage other-buf B1 */                         \
  { _Pragma("unroll") for (int mi_ = 0; mi_ < 4; ++mi_) {                      \
      a_[mi_][0] = rdA(HB, mi_, 0); a_[mi_][1] = rdA(HB, mi_, 1); }            \
    _Pragma("unroll") for (int ni_ = 0; ni_ < 2; ++ni_) {                      \
      bL[ni_][0] = rdB(HB, ni_, 0); bL[ni_][1] = rdB(HB, ni_, 1); } }          \
  STAGE(OB, 1, 1, ktB1);                                                       \
  __builtin_amdgcn_s_barrier();                                                \
  __builtin_amdgcn_s_setprio(1);                                               \
  MMQ(0, 0, bL)                                                                \
  __builtin_amdgcn_s_setprio(0);                                               \
  __builtin_amdgcn_s_barrier();                                                \
  /* P2: read B-hi(4) */                                                       \
  { _Pragma("unroll") for (int ni_ = 0; ni_ < 2; ++ni_) {                      \
      bH[ni_][0] = rdB(HB, 2 + ni_, 0); bH[ni_][1] = rdB(HB, 2 + ni_, 1); } }  \
  __builtin_amdgcn_s_barrier();                                                \
  __builtin_amdgcn_s_setprio(1);                                               \
  MMQ(0, 2, bH)                                                                \
  __builtin_amdgcn_s_setprio(0);                                               \
  __builtin_amdgcn_s_barrier();                                                \
  /* P3: read A-hi(8); stage own B0 (B free after P2) */                       \
  { _Pragma("unroll") for (int mi_ = 0; mi_ < 4; ++mi_) {                      \
      a_[mi_][0] = rdA(HB, 4 + mi_, 0); a_[mi_][1] = rdA(HB, 4 + mi_, 1); } }  \
  STAGE(HB, 1, 0, kt2);                                                        \
  __builtin_amdgcn_s_barrier();                                                \
  __builtin_amdgcn_s_setprio(1);                                               \
  MMQ(4, 2, bH)                                                                \
  __builtin_amdgcn_s_setprio(0);                                               \
  __builtin_amdgcn_s_barrier();                                                \
  /* P4: no reads; stage own A0+A1 (A free after P3); counted vmcnt */         \
  STAGE(HB, 0, 0, kt2);                                                        \
  STAGE(HB, 0, 1, kt2);                                                        \
  __builtin_amdgcn_s_barrier();                                                \
  __builtin_amdgcn_s_setprio(1);                                               \
  MMQ(4, 0, bL)                                                                \
  __builtin_amdgcn_s_setprio(0);                                               \
  asm volatile("s_waitcnt vmcnt(6)");                                          \
  __builtin_amdgcn_s_barrier();

  // prologue: tile0 -> buf0 (4 halves), tile1 -> buf1 (B0,A0,A1). 14 loads,
  // vmcnt(6) drains tile0's 8, leaves 3 half-tiles in flight.
  STAGE(0, 0, 0, 0); STAGE(0, 0, 1, 0); STAGE(0, 1, 0, 0); STAGE(0, 1, 1, 0);
  STAGE(1, 1, 0, 64); STAGE(1, 0, 0, 64); STAGE(1, 0, 1, 64);
  asm volatile("s_waitcnt vmcnt(6)");
  __builtin_amdgcn_s_barrier();

  const int NIT = NH / 128;   // 25 iterations, 2 K-tiles each
  for (int it = 0; it < NIT; ++it) {
    const int kbase = it * 128;
    const int kB1a = kbase + 64;                          // tile 2it+1 B1 (always valid)
    const int kt2a = (it < NIT - 1) ? kbase + 128 : 0;    // tile 2it+2 (clamped dangling)
    const int kB1b = kt2a;                                // tile 2it+2 B1
    const int kt2b = (it < NIT - 1) ? kbase + 192 : 0;    // tile 2it+3
    K_TILE(0, 1, kB1a, kt2a)
    K_TILE(1, 0, kB1b, kt2b)
  }
#undef STAGE
#undef MMQ
#undef K_TILE

  // epilogue: fused pair-gather + bias-prefolded relu; skip N-pad cols
#pragma unroll
  for (int mi = 0; mi < 8; ++mi) {
#pragma unroll
    for (int r = 0; r < 4; ++r) {
      int row = m0 + wr * 128 + mi * 16 + quad * 4 + r;
      int hp = pairs[2 * row], tp = pairs[2 * row + 1];
      int pb = (row >> 10) * NE_;
      const float* pAr = preAB_ + (size_t)(pb + hp) * KF;
      const float* pBr = preAB_ + NH + (size_t)(pb + tp) * KF;
#pragma unroll
      for (int ni = 0; ni < 4; ++ni) {
        int col = n0 + wc * 64 + ni * 16 + lane16;
        if (col < NH) {
          float v = acc[mi][ni][r] + pAr[col] + pBr[col];
          C[(size_t)row * NH + col] = f2bf(fmaxf(v, 0.f));
        }
      }
    }
  }
}

// ---------------------------------------------------------------- mlp2 partial reduce: out = sum_z part[z] + b2
__global__ __launch_bounds__(128) void k_out_reduce(
    const float* __restrict__ part, const float* __restrict__ b2,
    float* __restrict__ out) {
  int row = blockIdx.x, c = threadIdx.x;
  if (c >= OUT_) return;
  float s = b2[c];
#pragma unroll
  for (int z = 0; z < NZ; z++)
    s += part[(size_t)z * (B_ * P_ * 128) + (size_t)row * 128 + c];
  out[(size_t)row * OUT_ + c] = s;
}

// ---------------------------------------------------------------- edge aggregation (CSR)
__global__ __launch_bounds__(256) void k_agg(
    const u16* __restrict__ Hr, const int* __restrict__ rowptr,
    const int* __restrict__ elist, const float* __restrict__ gnn_b, int layer,
    float* __restrict__ hout, u16* __restrict__ houtB) {
  int n = blockIdx.x, b = blockIdx.y;
  int beg = rowptr[b * (N_ + 1) + n], end = rowptr[b * (N_ + 1) + n + 1];
  const int* el = elist + (size_t)b * E_;
  const u16* HrB = Hr + (size_t)b * N_ * NW;
  int tid = threadIdx.x;
  for (int c = tid; c < D_; c += 256) {
    float acc = bf2f(HrB[(size_t)n * NW + R_ * D_ + c]) + gnn_b[layer * D_ + c];
    for (int i = beg; i < end; i++) {
      int pk = el[i];
      acc += bf2f(HrB[(size_t)(pk & 511) * NW + (pk >> 9) * D_ + c]);
    }
    float r = fmaxf(acc, 0.f);
    hout[((size_t)b * N_ + n) * D_ + c] = r;
    houtB[((size_t)b * N_ + n) * D_ + c] = f2bf(r);
  }
}

// ---------------------------------------------------------------- entity mention-mean (f32 + bf16 out)
__global__ __launch_bounds__(256) void k_ent(
    const float* __restrict__ h0, const float* __restrict__ h1,
    const int* __restrict__ e2m, const float* __restrict__ e2m_mask,
    float* __restrict__ ent, u16* __restrict__ entB) {
  int e = blockIdx.x, b = blockIdx.y;
  __shared__ int idx_s[MM_];
  __shared__ float msk_s[MM_];
  int tid = threadIdx.x;
  if (tid < MM_) {
    idx_s[tid] = e2m[((size_t)b * NE_ + e) * MM_ + tid];
    msk_s[tid] = e2m_mask[((size_t)b * NE_ + e) * MM_ + tid];
  }
  __syncthreads();
  float msum = 0.f;
#pragma unroll
  for (int m = 0; m < MM_; m++) msum += msk_s[m];
  float inv = 1.f / (msum + 1e-7f);
  for (int c = tid; c < EE2; c += 256) {
    const float* base = (c < D_) ? h0 : h1;
    int cc = (c < D_) ? c : c - D_;
    float s = 0.f;
#pragma unroll
    for (int m = 0; m < MM_; m++) {
      int j = idx_s[m];
      if (j > 0) s += base[((size_t)b * N_ + (j - 1)) * D_ + cc] * msk_s[m];
    }
    float v = s * inv;
    ent[((size_t)b * NE_ + e) * EE2 + c] = v;
    entB[((size_t)b * NE_ + e) * EE2 + c] = f2bf(v);
  }
}

// ---------------------------------------------------------------- featC: [|hf-tf|, hf*tf] bf16 (4096 x 3200)
__global__ __launch_bounds__(256) void k_featC(
    const float* __restrict__ ent, const int* __restrict__ ent_pair,
    u16* __restrict__ featC) {
  int row = blockIdx.x;                 // 0..4095
  int b = row >> 10, g = row & 1023;
  int hp = ent_pair[(((size_t)b << 10) + g) * 2 + 0];
  int tp = ent_pair[(((size_t)b << 10) + g) * 2 + 1];
  const float* eh = ent + ((size_t)b * NE_ + hp) * EE2;
  const float* et = ent + ((size_t)b * NE_ + tp) * EE2;
  u16* orow = featC + (size_t)row * NH;
  for (int c = threadIdx.x; c < 800; c += 256) {   // float4 chunks, 2 segs
    int seg = c / 400, kk = (c - seg * 400) * 4;
    float4 hf = *(const float4*)(eh + kk);
    float4 tf = *(const float4*)(et + kk);
    float4 v;
    if (seg == 0) {
      v.x = fabsf(hf.x - tf.x); v.y = fabsf(hf.y - tf.y);
      v.z = fabsf(hf.z - tf.z); v.w = fabsf(hf.w - tf.w);
    } else {
      v.x = hf.x * tf.x; v.y = hf.y * tf.y;
      v.z = hf.z * tf.z; v.w = hf.w * tf.w;
    }
    ushort4 o;
    o.x = f2bf(v.x); o.y = f2bf(v.y); o.z = f2bf(v.z); o.w = f2bf(v.w);
    *(ushort4*)(orow + seg * EE2 + kk) = o;
  }
}

// ----------------------------------------------------------------
extern "C" void kernel_launch(void* const* d_in, const int* in_sizes, int n_in,
                              void* d_out, int out_size, void* d_ws, size_t ws_size,
                              hipStream_t stream) {
  const float* token_feature = (const float*)d_in[0];
  const float* doc_cls       = (const float*)d_in[1];
  const int*   span_pos      = (const int*)d_in[2];
  const float* span_mask     = (const float*)d_in[3];
  const int*   node_ner      = (const int*)d_in[4];
  const float* node_mask     = (const float*)d_in[5];
  const int*   e2m           = (const int*)d_in[6];
  const float* e2m_mask      = (const float*)d_in[7];
  const int*   ent_pair      = (const int*)d_in[8];
  const int*   edge_src      = (const int*)d_in[9];
  const int*   edge_dst      = (const int*)d_in[10];
  const int*   edge_rel      = (const int*)d_in[11];
  const int*   ment_num      = (const int*)d_in[12];
  const float* nerEmb        = (const float*)d_in[13];
  const float* doc_W         = (const float*)d_in[14];
  const float* doc_b         = (const float*)d_in[15];
  const float* W_rel         = (const float*)d_in[16];
  const float* W_self        = (const float*)d_in[17];
  const float* gnn_b         = (const float*)d_in[18];
  const float* W1            = (const float*)d_in[19];
  const float* b1            = (const float*)d_in[20];
  const float* W2            = (const float*)d_in[21];
  const float* b2            = (const float*)d_in[22];
  float* out = (float*)d_out;

  float* ws = (float*)d_ws;
  size_t off = 0;
  auto alloc = [&](size_t n) {
    float* p = ws + off;
    off += (n + 63) & ~size_t(63);
    return p;
  };
  float* doc_proj = alloc(B_ * D_);
  u16*   xB  = (u16*)alloc((size_t)B_ * N_ * D_ / 2);
  float* h0  = alloc((size_t)B_ * N_ * D_);
  float* h1  = alloc((size_t)B_ * N_ * D_);
  u16*   hB  = (u16*)alloc((size_t)B_ * N_ * D_ / 2);
  float* ent = alloc((size_t)B_ * NE_ * EE2);
  u16*   entB = (u16*)alloc((size_t)B_ * NE_ * EE2 / 2);
  u16*   WT    = (u16*)alloc((size_t)L_ * NW * D_ / 2);
  u16*   W1abT = (u16*)alloc((size_t)KF * EE2 / 2);      // 6400 x 1600
  u16*   W1cdT = (u16*)alloc((size_t)NPAD * NH / 2);     // 3328 x 3200 (N-padded)
  u16*   W2T   = (u16*)alloc((size_t)128 * NH / 2);
  float* preAB = alloc((size_t)B_ * NE_ * KF);           // 256 x 6400
  // Hr (1024x12800 u16) and featC (4096x3200 u16) same size; Hr dead after agg
  u16*   Hr    = (u16*)alloc((size_t)B_ * N_ * NW / 2);
  u16*   featC = Hr;
  u16*   hiddenB = (u16*)alloc((size_t)B_ * P_ * NH / 2);
  float* part    = alloc((size_t)NZ * B_ * P_ * 128);    // mlp2 partials
  int*   csr_cnt    = (int*)alloc(B_ * N_ / 1 * sizeof(int) / 4);
  int*   csr_rowptr = (int*)alloc(B_ * (N_ + 1));
  int*   csr_cursor = (int*)alloc(B_ * N_);
  int*   csr_elist  = (int*)alloc(B_ * E_);
  (void)ws_size;

  // CSR build (independent of everything; used by both agg layers)
  k_csr_zero<<<dim3(B_), 256, 0, stream>>>(csr_cnt);
  k_csr_count<<<dim3(E_ / 256, B_), 256, 0, stream>>>(edge_dst, csr_cnt);
  k_csr_scan<<<dim3(B_), 256, 0, stream>>>(csr_cnt, csr_rowptr, csr_cursor);
  k_csr_fill<<<dim3(E_ / 256, B_), 256, 0, stream>>>(edge_src, edge_dst, edge_rel,
                                                     csr_cursor, csr_elist);

  // weight prep (independent of data path)
  k_wt<<<dim3(D_ / 32, D_ / 32, L_ * 16), 256, 0, stream>>>(W_rel, W_self, WT);
  k_w1t<<<dim3(KF / 32, NH / 32), 256, 0, stream>>>(W1, W1abT, W1cdT);
  k_w1cd_pad<<<dim3(800), 256, 0, stream>>>(W1cdT);
  k_w2t<<<dim3(NH / 32, 4), 256, 0, stream>>>(W2, W2T);

  k_doc_proj<<<dim3((B_ * D_ + 255) / 256), 256, 0, stream>>>(doc_cls, doc_W, doc_b, doc_proj);
  k_build_node<<<dim3(N_, B_), 256, 0, stream>>>(token_feature, doc_cls, span_pos, span_mask,
                                                 node_ner, node_mask, ment_num, nerEmb,
                                                 doc_proj, xB);
  // GNN layers
  const u16* hin = xB;
  float* houts[2] = {h0, h1};
  for (int l = 0; l < L_; l++) {
    k_gemm_bt<D_, 0><<<dim3(NW / 128, (B_ * N_) / 128), 256, 0, stream>>>(
        hin, D_, WT + (size_t)l * NW * D_, D_, nullptr, nullptr, nullptr, nullptr,
        Hr, NW, 0, 0, 0);
    k_agg<<<dim3(N_, B_), 256, 0, stream>>>(Hr, csr_rowptr, csr_elist,
                                            gnn_b, l, houts[l], hB);
    hin = hB;
  }
  k_ent<<<dim3(NE_, B_), 256, 0, stream>>>(h0, h1, e2m, e2m_mask, ent, entB);

  // preAB = ent @ [W1a | W1b] (+b1 on a-half)   M=256, K=1600, N=6400
  k_gemm_bt<EE2, 4><<<dim3(KF / 128, (B_ * NE_) / 128), 256, 0, stream>>>(
      entB, EE2, W1abT, EE2, b1, nullptr, nullptr, nullptr, preAB, KF, 0, 0, 0);

  k_featC<<<dim3(B_ * P_), 256, 0, stream>>>(ent, ent_pair, featC);

  // big GEMM via 256x256 8-phase quadrant schedule:
  // hidden = relu(featC @ W1cd^T + preAB[hp][c] + preAB[tp][3200+c])
  k_gemm8p<<<dim3(NPAD / 256, (B_ * P_) / 256), 512, 0, stream>>>(
      featC, W1cdT, preAB, ent_pair, hiddenB);

  // mlp2 split-K partials: part[z] = hiddenB[:, z*800:(z+1)*800] @ W2T_k-slice^T
  k_gemm_bt<KS, 1><<<dim3(1, (B_ * P_) / 128, NZ), 256, 0, stream>>>(
      hiddenB, NH, W2T, NH, nullptr, nullptr, nullptr, nullptr, part, 128,
      0, KS, (long long)B_ * P_ * 128);
  k_out_reduce<<<dim3(B_ * P_), 128, 0, stream>>>(part, b2, out);
}

// Round 5
// 711.222 us; speedup vs baseline: 1.0552x; 1.0552x over previous
//
#include <hip/hip_runtime.h>
#include <hip/hip_bf16.h>

// Problem dims
#define B_    4
#define T_    512
#define H_    768
#define N_    256
#define S_    16
#define NERD  32
#define D_    800      // H + NER_DIM
#define L_    2
#define R_    15
#define NE_   64
#define MM_   8
#define P_    1024
#define E_    4096
#define OUT_  97
#define NW    12800        // GNN GEMM width: R*D + D  ([W_rel | W_self])
#define KP    896          // K-padded D for 8ph GNN GEMM (7 x 128)
#define EE2   1600         // 2*D
#define KF    (4 * EE2)    // 6400
#define NH    (2 * EE2)    // 3200
#define NPAD  3328         // 13*256  (N-padded W1cdT rows for 256-tile GEMM)
#define KS    800          // mlp2 K-split slice
#define NZ    4            // mlp2 K-split count

typedef unsigned short u16;
typedef unsigned int   u32;
typedef __attribute__((ext_vector_type(8))) short  short8;
typedef __attribute__((ext_vector_type(4))) float  f32x4;

#define AS1 __attribute__((address_space(1)))
#define AS3 __attribute__((address_space(3)))

static __device__ __forceinline__ u16 f2bf(float f) {
  union { float f; u32 u; } v; v.f = f;
  u32 u = v.u;
  u32 r = (u + 0x7FFFu + ((u >> 16) & 1u)) >> 16;  // round-nearest-even
  return (u16)r;
}
static __device__ __forceinline__ float bf2f(u16 h) {
  union { u32 u; float f; } v; v.u = ((u32)h) << 16;
  return v.f;
}

// ---------------------------------------------------------------- doc_proj
__global__ __launch_bounds__(256) void k_doc_proj(
    const float* __restrict__ doc_cls, const float* __restrict__ doc_W,
    const float* __restrict__ doc_b, float* __restrict__ doc_proj) {
  int i = blockIdx.x * 256 + threadIdx.x;
  if (i >= B_ * D_) return;
  int b = i / D_, d = i % D_;
  float acc = doc_b[d];
  const float* dc = doc_cls + b * H_;
#pragma unroll 4
  for (int k = 0; k < H_; k++) acc += dc[k] * doc_W[k * D_ + d];
  doc_proj[i] = fmaxf(acc, 0.f);
}

// ---------------------------------------------------------------- node build -> xB (bf16, rows KP-wide, zero pad)
__global__ __launch_bounds__(256) void k_build_node(
    const float* __restrict__ tokf, const float* __restrict__ doc_cls,
    const int* __restrict__ span_pos, const float* __restrict__ span_mask,
    const int* __restrict__ node_ner, const float* __restrict__ node_mask,
    const int* __restrict__ ment_num, const float* __restrict__ nerEmb,
    const float* __restrict__ doc_proj, u16* __restrict__ xB) {
  int n = blockIdx.x, b = blockIdx.y;
  __shared__ int pos_s[S_];
  __shared__ float msk_s[S_];
  int tid = threadIdx.x;
  if (tid < S_) {
    pos_s[tid] = span_pos[((size_t)b * N_ + n) * S_ + tid];
    msk_s[tid] = span_mask[((size_t)b * N_ + n) * S_ + tid];
  }
  __syncthreads();
  float msum = 0.f;
#pragma unroll
  for (int s = 0; s < S_; s++) msum += msk_s[s];
  float rinv = 1.f / (msum + 0.1f);
  int m = ment_num[b];
  float nm = node_mask[b * N_ + n];
  int ner = node_ner[b * N_ + n];
  for (int d = tid; d < KP; d += 256) {
    float v = 0.f;
    if (d < D_) {
      if (d < H_) {
        float ssum = 0.f;
#pragma unroll
        for (int s = 0; s < S_; s++)
          ssum += tokf[((size_t)b * T_ + pos_s[s]) * H_ + d] * msk_s[s];
        v = ssum * rinv + doc_cls[b * H_ + d];
      } else {
        v = nerEmb[ner * NERD + (d - H_)];
      }
      v *= nm;
      if (n == m) v = doc_proj[b * D_ + d];
    }
    xB[((size_t)b * N_ + n) * KP + d] = f2bf(v);
  }
}

// ---------------------------------------------------------------- GNN weight transpose (rows KP-wide)
__global__ __launch_bounds__(256) void k_wt(const float* __restrict__ W_rel,
                                            const float* __restrict__ W_self,
                                            u16* __restrict__ WT) {
  __shared__ float tile[32][33];
  int l = blockIdx.z >> 4, i = blockIdx.z & 15;
  const float* src = (i < 15) ? (W_rel + ((size_t)l * R_ + i) * D_ * D_)
                              : (W_self + (size_t)l * D_ * D_);
  u16* dst = WT + (size_t)l * NW * KP + (size_t)i * D_ * KP;
  int d0 = blockIdx.x * 32, e0 = blockIdx.y * 32;
  int tx = threadIdx.x & 31, ty = threadIdx.x >> 5;
  for (int j = ty; j < 32; j += 8)
    tile[j][tx] = src[(size_t)(d0 + j) * D_ + e0 + tx];
  __syncthreads();
  for (int j = ty; j < 32; j += 8)
    dst[(size_t)(e0 + j) * KP + d0 + tx] = f2bf(tile[tx][j]);
}

// zero pad cols 800..895 of all 2*NW WT rows: 25600 rows x 48 u32
__global__ __launch_bounds__(256) void k_wt_pad(u16* __restrict__ WT) {
  size_t i = (size_t)blockIdx.x * 256 + threadIdx.x;   // 0..1228799
  size_t row = i / 48, c = i % 48;
  ((u32*)(WT + row * KP + D_))[c] = 0u;
}

// ---------------------------------------------------------------- W1 transpose:
// W1 (KF x NH fp32) ->  W1abT (6400 x 1600 bf16)  rows: n for a-part, 3200+n for b-part
//                       W1cdT (NPAD x 3200 bf16)  rows: n, k = kcol-3200 (rows >=NH zero-padded)
__global__ __launch_bounds__(256) void k_w1t(const float* __restrict__ W1,
                                             u16* __restrict__ W1abT,
                                             u16* __restrict__ W1cdT) {
  __shared__ float tile[32][33];
  int k0 = blockIdx.x * 32, n0 = blockIdx.y * 32;
  int tx = threadIdx.x & 31, ty = threadIdx.x >> 5;
  for (int i = ty; i < 32; i += 8)
    tile[i][tx] = W1[(size_t)(k0 + i) * NH + n0 + tx];
  __syncthreads();
  for (int i = ty; i < 32; i += 8) {
    int kk = k0 + tx, n = n0 + i;
    u16 v = f2bf(tile[tx][i]);
    if (kk < EE2)            W1abT[(size_t)n * EE2 + kk] = v;
    else if (kk < 2 * EE2)   W1abT[(size_t)(NH + n) * EE2 + (kk - EE2)] = v;
    else                     W1cdT[(size_t)n * NH + (kk - 2 * EE2)] = v;
  }
}

// zero the N-pad rows of W1cdT (rows NH..NPAD-1), 128*3200 u16 = 204800 u32
__global__ __launch_bounds__(256) void k_w1cd_pad(u16* __restrict__ W1cdT) {
  size_t i = (size_t)blockIdx.x * 256 + threadIdx.x;   // 0..204799
  ((u32*)(W1cdT + (size_t)NH * NH))[i] = 0u;
}

// ---------------------------------------------------------------- W2 transpose: W2 (NH x 97 fp32) -> W2T (128 x NH bf16), pad rows zero
__global__ __launch_bounds__(256) void k_w2t(const float* __restrict__ W2,
                                             u16* __restrict__ W2T) {
  __shared__ float tile[32][33];
  int k0 = blockIdx.x * 32, n0 = blockIdx.y * 32;
  int tx = threadIdx.x & 31, ty = threadIdx.x >> 5;
  for (int i = ty; i < 32; i += 8)
    tile[i][tx] = (n0 + tx < OUT_) ? W2[(size_t)(k0 + i) * OUT_ + n0 + tx] : 0.f;
  __syncthreads();
  for (int i = ty; i < 32; i += 8)
    W2T[(size_t)(n0 + i) * NH + k0 + tx] = f2bf(tile[tx][i]);
}

// ---------------------------------------------------------------- CSR build
__global__ __launch_bounds__(256) void k_csr_zero(int* __restrict__ cnt) {
  cnt[blockIdx.x * 256 + threadIdx.x] = 0;
}
__global__ __launch_bounds__(256) void k_csr_count(const int* __restrict__ edst,
                                                   int* __restrict__ cnt) {
  int e = blockIdx.x * 256 + threadIdx.x, b = blockIdx.y;
  atomicAdd(&cnt[b * N_ + edst[(size_t)b * E_ + e]], 1);
}
__global__ __launch_bounds__(256) void k_csr_scan(const int* __restrict__ cnt,
                                                  int* __restrict__ rowptr,
                                                  int* __restrict__ cursor) {
  int b = blockIdx.x, t = threadIdx.x;
  __shared__ int s[N_];
  int own = cnt[b * N_ + t];
  s[t] = own;
  __syncthreads();
  for (int off = 1; off < N_; off <<= 1) {
    int v = (t >= off) ? s[t - off] : 0;
    __syncthreads();
    s[t] += v;
    __syncthreads();
  }
  int excl = s[t] - own;
  rowptr[b * (N_ + 1) + t] = excl;
  cursor[b * N_ + t] = excl;
  if (t == 0) rowptr[b * (N_ + 1) + N_] = E_;
}
__global__ __launch_bounds__(256) void k_csr_fill(
    const int* __restrict__ esrc, const int* __restrict__ edst,
    const int* __restrict__ erel, int* __restrict__ cursor,
    int* __restrict__ elist) {
  int e = blockIdx.x * 256 + threadIdx.x, b = blockIdx.y;
  size_t ei = (size_t)b * E_ + e;
  int pos = atomicAdd(&cursor[b * N_ + edst[ei]], 1);
  elist[b * E_ + pos] = esrc[ei] | (erel[ei] << 9);
}

// ---------------------------------------------------------------- generic bf16 MFMA GEMM (m97-style)
// C = A[M x K](lda) @ B[N x K](ldb)^T ; 128x128 tile, BK=32, group-M swizzle.
// EPI: 1 = f32 plain, 4 = f32 acc + (col<NH ? bias[col] : 0)
template <int KD, int EPI>
__global__ __launch_bounds__(256) void k_gemm_bt(
    const u16* __restrict__ A, int lda, const u16* __restrict__ Bm, int ldb,
    const float* __restrict__ bias,
    void* __restrict__ Cv, int ldc, long long zA, long long zC) {
  __shared__ u16 As[128 * 32];
  __shared__ u16 Bs[128 * 32];
  int tid = threadIdx.x;
  int w = tid >> 6, lane = tid & 63;
  int wr = w >> 1, wc = w & 1;
  int lane16 = lane & 15, quad = lane >> 4;

  // group-M swizzle for L2 locality
  int nbn = gridDim.x, nbm = gridDim.y;
  int pid = blockIdx.y * nbn + blockIdx.x;
  const int GROUP = 8;
  int npg = GROUP * nbn;
  int gidg = pid / npg;
  int first = gidg * GROUP;
  int szm = min(nbm - first, GROUP);
  int pid_m = first + (pid % npg) % szm;
  int pid_n = (pid % npg) / szm;
  int n0 = pid_n * 128;
  int m0 = pid_m * 128;

  int lrow = lane >> 2;              // 0..15
  int lcol = (lane & 3) * 8;         // ushort offset within 32-col row

  f32x4 acc[4][4] = {};

  const u16* gA = A + (size_t)blockIdx.z * zA + (size_t)m0 * lda;
  const u16* gB = Bm + (size_t)blockIdx.z * zA + (size_t)n0 * ldb;

  for (int kt = 0; kt < KD; kt += 32) {
    __syncthreads();
#pragma unroll
    for (int j = 0; j < 2; j++) {
      int chunk = j * 4 + w;
      int row = chunk * 16 + lrow;
      __builtin_amdgcn_global_load_lds(
          (const AS1 void*)(gA + (size_t)row * lda + kt + lcol),
          (AS3 void*)(As + chunk * 512 + lane * 8), 16, 0, 0);
      __builtin_amdgcn_global_load_lds(
          (const AS1 void*)(gB + (size_t)row * ldb + kt + lcol),
          (AS3 void*)(Bs + chunk * 512 + lane * 8), 16, 0, 0);
    }
    __syncthreads();

    short8 af[4], bf[4];
#pragma unroll
    for (int mi = 0; mi < 4; mi++) {
      int ml = wr * 64 + mi * 16 + lane16;
      af[mi] = *(const short8*)(As + ml * 32 + quad * 8);
    }
#pragma unroll
    for (int ni = 0; ni < 4; ni++) {
      int nl = wc * 64 + ni * 16 + lane16;
      bf[ni] = *(const short8*)(Bs + nl * 32 + quad * 8);
    }
#pragma unroll
    for (int mi = 0; mi < 4; mi++)
#pragma unroll
      for (int ni = 0; ni < 4; ni++)
        acc[mi][ni] = __builtin_amdgcn_mfma_f32_16x16x32_bf16(
            af[mi], bf[ni], acc[mi][ni], 0, 0, 0);
  }

  // epilogue: D layout col=lane&15, row=quad*4+reg
  int cols[4];
  float bv[4];
#pragma unroll
  for (int ni = 0; ni < 4; ni++) {
    cols[ni] = n0 + wc * 64 + ni * 16 + lane16;
    if (EPI == 4) bv[ni] = (cols[ni] < NH) ? bias[cols[ni]] : 0.f;
  }
  float* Cf = (float*)Cv + (size_t)blockIdx.z * zC;
#pragma unroll
  for (int mi = 0; mi < 4; mi++) {
#pragma unroll
    for (int r = 0; r < 4; r++) {
      int row = m0 + wr * 64 + mi * 16 + quad * 4 + r;
#pragma unroll
      for (int ni = 0; ni < 4; ni++) {
        float v = acc[mi][ni][r];
        int col = cols[ni];
        if (EPI == 1) {
          Cf[(size_t)row * ldc + col] = v;
        } else if (EPI == 4) {
          Cf[(size_t)row * ldc + col] = v + bv[ni];
        }
      }
    }
  }
}

// ---------------------------------------------------------------- 256x256 quadrant-8ph GEMM (T1+T2+T3+T4+T5)
// C = A[M x K](LDX) @ B[N x K](LDX)^T, bf16 out (LDC row stride).
// EPI 0: plain bf16 store (GNN Hr). EPI 2: relu(acc + preAB[hp][col] + preAB[tp][NH+col]),
//        skip cols >= NH (mlp1 hidden).
// 512 thr (8 waves 2Mx4N); LDS 128KB [buf][A/B][half][128x64], XOR-swizzled 16B granules.
// Quadrant phasing: reads 12/4/8/0 ds_read_b128 across P1..P4; one C-quadrant x K=64
// per phase; counted vmcnt(6) once per K-tile (never 0 in loop).
template <int LDX, int NIT, int NBN, int LDC, int EPI>
__global__ __launch_bounds__(512, 2) void k_gemm8p(
    const u16* __restrict__ A, const u16* __restrict__ Bm,
    const float* __restrict__ preAB_, const int* __restrict__ pairs,
    u16* __restrict__ C) {
  __shared__ u16 lds[2][2][2][128 * 64];   // strides: buf 65536 B, A/B 32768, half 16384

  int tid = threadIdx.x;
  int w = tid >> 6, lane = tid & 63;
  int wr = w >> 2, wc = w & 3;             // 2 x 4 wave grid
  int lane16 = lane & 15, quad = lane >> 4;

  // XCD-aware bijective swizzle (nwg divisible by 8 for both instantiations)
  int pid = blockIdx.y * NBN + blockIdx.x;
  const int CPX = (NBN * 0 + (int)0) ? 0 : 0;  // (placeholder, folded below)
  int nwg = NBN * gridDim.y;
  int cpx = nwg >> 3;
  pid = (pid & 7) * cpx + (pid >> 3);
  int pid_m = pid / NBN, pid_n = pid % NBN;
  int m0 = pid_m * 256, n0 = pid_n * 256;

  // staging per-thread constants: row-in-quarter + pre-swizzled source granule
  int srow = (w << 3) + (lane >> 3);                 // 0..63
  int g8 = ((lane & 7) ^ (lane >> 3)) << 3;          // source col elems (granule*8)
  const u16* gAt = A + (size_t)(m0 + srow) * LDX + g8;
  const u16* gBt = Bm + (size_t)(n0 + srow) * LDX + g8;
  int ldsSlot = ((w << 6) + lane) << 3;              // u16 elems within half

  // one STAGE = one 128x64 half-tile = 2 x global_load_lds(16B) per thread
#define STAGE(buf, ab, h, kt)                                                  \
  do {                                                                         \
    const u16* gsrc_ = (ab) ? gBt : gAt;                                       \
    __builtin_amdgcn_global_load_lds(                                          \
        (const AS1 void*)(gsrc_ + (size_t)((h)*128) * LDX + (kt)),             \
        (AS3 void*)(&lds[buf][ab][h][0] + ldsSlot), 16, 0, 0);                 \
    __builtin_amdgcn_global_load_lds(                                          \
        (const AS1 void*)(gsrc_ + (size_t)((h)*128 + 64) * LDX + (kt)),        \
        (AS3 void*)(&lds[buf][ab][h][0] + 4096 + ldsSlot), 16, 0, 0);          \
  } while (0)

  // plain-C++ swizzled fragment reads (compiler tracks deps -> counted lgkm)
  auto rdA = [&](int buf, int mi, int ks) -> short8 {
    int rh = mi * 16 + lane16;
    int p = ((ks << 2) + quad) ^ (lane16 & 7);
    return *(const short8*)(&lds[buf][0][wr][(rh << 6) + (p << 3)]);
  };
  auto rdB = [&](int buf, int ni, int ks) -> short8 {
    int rh = ((wc & 1) << 6) + ni * 16 + lane16;
    int p = ((ks << 2) + quad) ^ (lane16 & 7);
    return *(const short8*)(&lds[buf][1][wc >> 1][(rh << 6) + (p << 3)]);
  };

  f32x4 acc[8][4] = {};
  short8 a_[4][2];     // current A quarter (lo in P1-P2, hi in P3-P4)
  short8 bL[2][2];     // ni{0,1} x ks, held P1 -> P4
  short8 bH[2][2];     // ni{2,3} x ks, held P2 -> P3

  // one C-quadrant x K=64: 8 acc tiles, each a K-chained MFMA pair
#define MMQ(MI0, NI0, BB)                                                      \
  { _Pragma("unroll") for (int mi_ = 0; mi_ < 4; ++mi_) {                      \
      _Pragma("unroll") for (int ni_ = 0; ni_ < 2; ++ni_) {                    \
        f32x4 t_ = __builtin_amdgcn_mfma_f32_16x16x32_bf16(                    \
            a_[mi_][0], BB[ni_][0], acc[(MI0) + mi_][(NI0) + ni_], 0, 0, 0);   \
        acc[(MI0) + mi_][(NI0) + ni_] =                                        \
            __builtin_amdgcn_mfma_f32_16x16x32_bf16(a_[mi_][1], BB[ni_][1],    \
                                                    t_, 0, 0, 0);              \
      } } }

  // one K-tile (K=64) in buf HB; OB = other buf. 4 quadrant phases.
#define K_TILE(HB, OB, ktB1, kt2)                                              \
  /* P1: read A-lo(8) + B-lo(4); stage other-buf B1 */                         \
  { _Pragma("unroll") for (int mi_ = 0; mi_ < 4; ++mi_) {                      \
      a_[mi_][0] = rdA(HB, mi_, 0); a_[mi_][1] = rdA(HB, mi_, 1); }            \
    _Pragma("unroll") for (int ni_ = 0; ni_ < 2; ++ni_) {                      \
      bL[ni_][0] = rdB(HB, ni_, 0); bL[ni_][1] = rdB(HB, ni_, 1); } }          \
  STAGE(OB, 1, 1, ktB1);                                                       \
  __builtin_amdgcn_s_barrier();                                                \
  __builtin_amdgcn_s_setprio(1);                                               \
  MMQ(0, 0, bL)                                                                \
  __builtin_amdgcn_s_setprio(0);                                               \
  __builtin_amdgcn_s_barrier();                                                \
  /* P2: read B-hi(4) */                                                       \
  { _Pragma("unroll") for (int ni_ = 0; ni_ < 2; ++ni_) {                      \
      bH[ni_][0] = rdB(HB, 2 + ni_, 0); bH[ni_][1] = rdB(HB, 2 + ni_, 1); } }  \
  __builtin_amdgcn_s_barrier();                                                \
  __builtin_amdgcn_s_setprio(1);                                               \
  MMQ(0, 2, bH)                                                                \
  __builtin_amdgcn_s_setprio(0);                                               \
  __builtin_amdgcn_s_barrier();                                                \
  /* P3: read A-hi(8); stage own B0 (B free after P2) */                       \
  { _Pragma("unroll") for (int mi_ = 0; mi_ < 4; ++mi_) {                      \
      a_[mi_][0] = rdA(HB, 4 + mi_, 0); a_[mi_][1] = rdA(HB, 4 + mi_, 1); } }  \
  STAGE(HB, 1, 0, kt2);                                                        \
  __builtin_amdgcn_s_barrier();                                                \
  __builtin_amdgcn_s_setprio(1);                                               \
  MMQ(4, 2, bH)                                                                \
  __builtin_amdgcn_s_setprio(0);                                               \
  __builtin_amdgcn_s_barrier();                                                \
  /* P4: no reads; stage own A0+A1 (A free after P3); counted vmcnt */         \
  STAGE(HB, 0, 0, kt2);                                                        \
  STAGE(HB, 0, 1, kt2);                                                        \
  __builtin_amdgcn_s_barrier();                                                \
  __builtin_amdgcn_s_setprio(1);                                               \
  MMQ(4, 0, bL)                                                                \
  __builtin_amdgcn_s_setprio(0);                                               \
  asm volatile("s_waitcnt vmcnt(6)");                                          \
  __builtin_amdgcn_s_barrier();

  // prologue: tile0 -> buf0 (4 halves), tile1 -> buf1 (B0,A0,A1). 14 loads,
  // vmcnt(6) drains tile0's 8, leaves 3 half-tiles in flight.
  STAGE(0, 0, 0, 0); STAGE(0, 0, 1, 0); STAGE(0, 1, 0, 0); STAGE(0, 1, 1, 0);
  STAGE(1, 1, 0, 64); STAGE(1, 0, 0, 64); STAGE(1, 0, 1, 64);
  asm volatile("s_waitcnt vmcnt(6)");
  __builtin_amdgcn_s_barrier();

  for (int it = 0; it < NIT; ++it) {
    const int kbase = it * 128;
    const int kB1a = kbase + 64;                          // tile 2it+1 B1 (always valid)
    const int kt2a = (it < NIT - 1) ? kbase + 128 : 0;    // tile 2it+2 (clamped dangling)
    const int kB1b = kt2a;                                // tile 2it+2 B1
    const int kt2b = (it < NIT - 1) ? kbase + 192 : 0;    // tile 2it+3
    K_TILE(0, 1, kB1a, kt2a)
    K_TILE(1, 0, kB1b, kt2b)
  }
#undef STAGE
#undef MMQ
#undef K_TILE

  // epilogue
#pragma unroll
  for (int mi = 0; mi < 8; ++mi) {
#pragma unroll
    for (int r = 0; r < 4; ++r) {
      int row = m0 + wr * 128 + mi * 16 + quad * 4 + r;
      const float* pAr = nullptr;
      const float* pBr = nullptr;
      if (EPI == 2) {
        int hp = pairs[2 * row], tp = pairs[2 * row + 1];
        int pb = (row >> 10) * NE_;
        pAr = preAB_ + (size_t)(pb + hp) * KF;
        pBr = preAB_ + NH + (size_t)(pb + tp) * KF;
      }
#pragma unroll
      for (int ni = 0; ni < 4; ++ni) {
        int col = n0 + wc * 64 + ni * 16 + lane16;
        if (EPI == 0) {
          C[(size_t)row * LDC + col] = f2bf(acc[mi][ni][r]);
        } else if (EPI == 2) {
          if (col < NH) {
            float v = acc[mi][ni][r] + pAr[col] + pBr[col];
            C[(size_t)row * LDC + col] = f2bf(fmaxf(v, 0.f));
          }
        }
      }
    }
  }
}

// ---------------------------------------------------------------- mlp2 partial reduce: out = sum_z part[z] + b2
__global__ __launch_bounds__(128) void k_out_reduce(
    const float* __restrict__ part, const float* __restrict__ b2,
    float* __restrict__ out) {
  int row = blockIdx.x, c = threadIdx.x;
  if (c >= OUT_) return;
  float s = b2[c];
#pragma unroll
  for (int z = 0; z < NZ; z++)
    s += part[(size_t)z * (B_ * P_ * 128) + (size_t)row * 128 + c];
  out[(size_t)row * OUT_ + c] = s;
}

// ---------------------------------------------------------------- edge aggregation (CSR)
// hout: f32 rows D_-wide; houtB: bf16 rows KP-wide with zero pad cols
__global__ __launch_bounds__(256) void k_agg(
    const u16* __restrict__ Hr, const int* __restrict__ rowptr,
    const int* __restrict__ elist, const float* __restrict__ gnn_b, int layer,
    float* __restrict__ hout, u16* __restrict__ houtB) {
  int n = blockIdx.x, b = blockIdx.y;
  int beg = rowptr[b * (N_ + 1) + n], end = rowptr[b * (N_ + 1) + n + 1];
  const int* el = elist + (size_t)b * E_;
  const u16* HrB = Hr + (size_t)b * N_ * NW;
  int tid = threadIdx.x;
  for (int c = tid; c < KP; c += 256) {
    if (c < D_) {
      float acc = bf2f(HrB[(size_t)n * NW + R_ * D_ + c]) + gnn_b[layer * D_ + c];
      for (int i = beg; i < end; i++) {
        int pk = el[i];
        acc += bf2f(HrB[(size_t)(pk & 511) * NW + (pk >> 9) * D_ + c]);
      }
      float r = fmaxf(acc, 0.f);
      hout[((size_t)b * N_ + n) * D_ + c] = r;
      houtB[((size_t)b * N_ + n) * KP + c] = f2bf(r);
    } else {
      houtB[((size_t)b * N_ + n) * KP + c] = 0;
    }
  }
}

// ---------------------------------------------------------------- entity mention-mean (f32 + bf16 out)
__global__ __launch_bounds__(256) void k_ent(
    const float* __restrict__ h0, const float* __restrict__ h1,
    const int* __restrict__ e2m, const float* __restrict__ e2m_mask,
    float* __restrict__ ent, u16* __restrict__ entB) {
  int e = blockIdx.x, b = blockIdx.y;
  __shared__ int idx_s[MM_];
  __shared__ float msk_s[MM_];
  int tid = threadIdx.x;
  if (tid < MM_) {
    idx_s[tid] = e2m[((size_t)b * NE_ + e) * MM_ + tid];
    msk_s[tid] = e2m_mask[((size_t)b * NE_ + e) * MM_ + tid];
  }
  __syncthreads();
  float msum = 0.f;
#pragma unroll
  for (int m = 0; m < MM_; m++) msum += msk_s[m];
  float inv = 1.f / (msum + 1e-7f);
  for (int c = tid; c < EE2; c += 256) {
    const float* base = (c < D_) ? h0 : h1;
    int cc = (c < D_) ? c : c - D_;
    float s = 0.f;
#pragma unroll
    for (int m = 0; m < MM_; m++) {
      int j = idx_s[m];
      if (j > 0) s += base[((size_t)b * N_ + (j - 1)) * D_ + cc] * msk_s[m];
    }
    float v = s * inv;
    ent[((size_t)b * NE_ + e) * EE2 + c] = v;
    entB[((size_t)b * NE_ + e) * EE2 + c] = f2bf(v);
  }
}

// ---------------------------------------------------------------- featC: [|hf-tf|, hf*tf] bf16 (4096 x 3200)
__global__ __launch_bounds__(256) void k_featC(
    const float* __restrict__ ent, const int* __restrict__ ent_pair,
    u16* __restrict__ featC) {
  int row = blockIdx.x;                 // 0..4095
  int b = row >> 10, g = row & 1023;
  int hp = ent_pair[(((size_t)b << 10) + g) * 2 + 0];
  int tp = ent_pair[(((size_t)b << 10) + g) * 2 + 1];
  const float* eh = ent + ((size_t)b * NE_ + hp) * EE2;
  const float* et = ent + ((size_t)b * NE_ + tp) * EE2;
  u16* orow = featC + (size_t)row * NH;
  for (int c = threadIdx.x; c < 800; c += 256) {   // float4 chunks, 2 segs
    int seg = c / 400, kk = (c - seg * 400) * 4;
    float4 hf = *(const float4*)(eh + kk);
    float4 tf = *(const float4*)(et + kk);
    float4 v;
    if (seg == 0) {
      v.x = fabsf(hf.x - tf.x); v.y = fabsf(hf.y - tf.y);
      v.z = fabsf(hf.z - tf.z); v.w = fabsf(hf.w - tf.w);
    } else {
      v.x = hf.x * tf.x; v.y = hf.y * tf.y;
      v.z = hf.z * tf.z; v.w = hf.w * tf.w;
    }
    ushort4 o;
    o.x = f2bf(v.x); o.y = f2bf(v.y); o.z = f2bf(v.z); o.w = f2bf(v.w);
    *(ushort4*)(orow + seg * EE2 + kk) = o;
  }
}

// ----------------------------------------------------------------
extern "C" void kernel_launch(void* const* d_in, const int* in_sizes, int n_in,
                              void* d_out, int out_size, void* d_ws, size_t ws_size,
                              hipStream_t stream) {
  const float* token_feature = (const float*)d_in[0];
  const float* doc_cls       = (const float*)d_in[1];
  const int*   span_pos      = (const int*)d_in[2];
  const float* span_mask     = (const float*)d_in[3];
  const int*   node_ner      = (const int*)d_in[4];
  const float* node_mask     = (const float*)d_in[5];
  const int*   e2m           = (const int*)d_in[6];
  const float* e2m_mask      = (const float*)d_in[7];
  const int*   ent_pair      = (const int*)d_in[8];
  const int*   edge_src      = (const int*)d_in[9];
  const int*   edge_dst      = (const int*)d_in[10];
  const int*   edge_rel      = (const int*)d_in[11];
  const int*   ment_num      = (const int*)d_in[12];
  const float* nerEmb        = (const float*)d_in[13];
  const float* doc_W         = (const float*)d_in[14];
  const float* doc_b         = (const float*)d_in[15];
  const float* W_rel         = (const float*)d_in[16];
  const float* W_self        = (const float*)d_in[17];
  const float* gnn_b         = (const float*)d_in[18];
  const float* W1            = (const float*)d_in[19];
  const float* b1            = (const float*)d_in[20];
  const float* W2            = (const float*)d_in[21];
  const float* b2            = (const float*)d_in[22];
  float* out = (float*)d_out;

  float* ws = (float*)d_ws;
  size_t off = 0;
  auto alloc = [&](size_t n) {
    float* p = ws + off;
    off += (n + 63) & ~size_t(63);
    return p;
  };
  float* doc_proj = alloc(B_ * D_);
  u16*   xB  = (u16*)alloc((size_t)B_ * N_ * KP / 2);
  float* h0  = alloc((size_t)B_ * N_ * D_);
  float* h1  = alloc((size_t)B_ * N_ * D_);
  u16*   hB  = (u16*)alloc((size_t)B_ * N_ * KP / 2);
  float* ent = alloc((size_t)B_ * NE_ * EE2);
  u16*   entB = (u16*)alloc((size_t)B_ * NE_ * EE2 / 2);
  u16*   WT    = (u16*)alloc((size_t)L_ * NW * KP / 2);
  u16*   W1abT = (u16*)alloc((size_t)KF * EE2 / 2);      // 6400 x 1600
  u16*   W1cdT = (u16*)alloc((size_t)NPAD * NH / 2);     // 3328 x 3200 (N-padded)
  u16*   W2T   = (u16*)alloc((size_t)128 * NH / 2);
  float* preAB = alloc((size_t)B_ * NE_ * KF);           // 256 x 6400
  // Hr (1024x12800 u16) and featC (4096x3200 u16) same size; Hr dead after agg
  u16*   Hr    = (u16*)alloc((size_t)B_ * N_ * NW / 2);
  u16*   featC = Hr;
  u16*   hiddenB = (u16*)alloc((size_t)B_ * P_ * NH / 2);
  float* part    = alloc((size_t)NZ * B_ * P_ * 128);    // mlp2 partials
  int*   csr_cnt    = (int*)alloc(B_ * N_ / 1 * sizeof(int) / 4);
  int*   csr_rowptr = (int*)alloc(B_ * (N_ + 1));
  int*   csr_cursor = (int*)alloc(B_ * N_);
  int*   csr_elist  = (int*)alloc(B_ * E_);
  (void)ws_size;

  // CSR build (independent of everything; used by both agg layers)
  k_csr_zero<<<dim3(B_), 256, 0, stream>>>(csr_cnt);
  k_csr_count<<<dim3(E_ / 256, B_), 256, 0, stream>>>(edge_dst, csr_cnt);
  k_csr_scan<<<dim3(B_), 256, 0, stream>>>(csr_cnt, csr_rowptr, csr_cursor);
  k_csr_fill<<<dim3(E_ / 256, B_), 256, 0, stream>>>(edge_src, edge_dst, edge_rel,
                                                     csr_cursor, csr_elist);

  // weight prep (independent of data path)
  k_wt<<<dim3(D_ / 32, D_ / 32, L_ * 16), 256, 0, stream>>>(W_rel, W_self, WT);
  k_wt_pad<<<dim3(4800), 256, 0, stream>>>(WT);
  k_w1t<<<dim3(KF / 32, NH / 32), 256, 0, stream>>>(W1, W1abT, W1cdT);
  k_w1cd_pad<<<dim3(800), 256, 0, stream>>>(W1cdT);
  k_w2t<<<dim3(NH / 32, 4), 256, 0, stream>>>(W2, W2T);

  k_doc_proj<<<dim3((B_ * D_ + 255) / 256), 256, 0, stream>>>(doc_cls, doc_W, doc_b, doc_proj);
  k_build_node<<<dim3(N_, B_), 256, 0, stream>>>(token_feature, doc_cls, span_pos, span_mask,
                                                 node_ner, node_mask, ment_num, nerEmb,
                                                 doc_proj, xB);
  // GNN layers: Hr = hin @ WT^T via quadrant-8ph 256x256 (K padded to 896)
  const u16* hin = xB;
  float* houts[2] = {h0, h1};
  for (int l = 0; l < L_; l++) {
    k_gemm8p<KP, KP / 128, NW / 256, NW, 0><<<dim3(NW / 256, (B_ * N_) / 256), 512, 0, stream>>>(
        hin, WT + (size_t)l * NW * KP, nullptr, nullptr, Hr);
    k_agg<<<dim3(N_, B_), 256, 0, stream>>>(Hr, csr_rowptr, csr_elist,
                                            gnn_b, l, houts[l], hB);
    hin = hB;
  }
  k_ent<<<dim3(NE_, B_), 256, 0, stream>>>(h0, h1, e2m, e2m_mask, ent, entB);

  // preAB = ent @ [W1a | W1b] (+b1 on a-half)   M=256, K=1600, N=6400
  k_gemm_bt<EE2, 4><<<dim3(KF / 128, (B_ * NE_) / 128), 256, 0, stream>>>(
      entB, EE2, W1abT, EE2, b1, preAB, KF, 0, 0);

  k_featC<<<dim3(B_ * P_), 256, 0, stream>>>(ent, ent_pair, featC);

  // big GEMM via 256x256 quadrant-8ph:
  // hidden = relu(featC @ W1cd^T + preAB[hp][c] + preAB[tp][3200+c])
  k_gemm8p<NH, NH / 128, NPAD / 256, NH, 2><<<dim3(NPAD / 256, (B_ * P_) / 256), 512, 0, stream>>>(
      featC, W1cdT, preAB, ent_pair, hiddenB);

  // mlp2 split-K partials: part[z] = hiddenB[:, z*800:(z+1)*800] @ W2T_k-slice^T
  k_gemm_bt<KS, 1><<<dim3(1, (B_ * P_) / 128, NZ), 256, 0, stream>>>(
      hiddenB, NH, W2T, NH, nullptr, part, 128, KS, (long long)B_ * P_ * 128);
  k_out_reduce<<<dim3(B_ * P_), 128, 0, stream>>>(part, b2, out);
}